// Round 1
// baseline (394.086 us; speedup 1.0000x reference)
//
#include <hip/hip_runtime.h>

// QuadNeighborhoodEncoderDeepsets on gfx950.
// Fused: layer1 (K=6, fp32 VALU) -> bf16 LDS A-tile -> layer2 via
// mfma_f32_16x16x32_bf16 with persistent W2^T fragments in VGPRs ->
// tanh epilogue -> mean over 6 neighbors.

#define HID     256
#define OBSD    54
#define SELFD   18
#define TILE_B  8
#define TILE_R  48           // 8 batches * 6 neighbors
#define LDA     264          // bf16 elems, padded +8 -> 2-way LDS conflicts only
#define LDH     260          // fp32 elems, padded +4
#define BATCHN  131072
#define NTILES  (BATCHN / TILE_B)
#define GRID_WG 2048

typedef __attribute__((ext_vector_type(8))) short bf16x8;   // 8 bf16 bits (4 VGPRs)
typedef __attribute__((ext_vector_type(4))) short s16x4;
typedef __attribute__((ext_vector_type(4))) float f32x4;

// tanh(x) = 1 - 2/(exp(2x)+1); exp(2x) = exp2(x * 2/ln2). v_exp_f32 + v_rcp_f32.
__device__ __forceinline__ float fast_tanh(float x) {
    float t = __builtin_amdgcn_exp2f(x * 2.8853900817779268f);
    return 1.0f - 2.0f * __builtin_amdgcn_rcpf(t + 1.0f);
}

// fp32 -> bf16 bits, round-to-nearest-even (inputs are never NaN here).
__device__ __forceinline__ short f2bf(float f) {
    unsigned u = __float_as_uint(f);
    u += 0x7fffu + ((u >> 16) & 1u);
    return (short)(u >> 16);
}

// W2 (256x256 fp32, [k][n]) -> W2^T (bf16 bits, [n][k]) in workspace.
__global__ void prep_w2t(const float* __restrict__ w2, short* __restrict__ w2t) {
    int idx = blockIdx.x * 256 + threadIdx.x;   // idx = n*256 + k
    int n = idx >> 8;
    int k = idx & 255;
    w2t[idx] = f2bf(w2[k * 256 + n]);
}

__global__ __launch_bounds__(256, 2) void qenc_main(
        const float* __restrict__ obs,
        const float* __restrict__ W1,
        const float* __restrict__ b1,
        const short* __restrict__ w2t,
        const float* __restrict__ b2,
        float* __restrict__ out)
{
    __shared__ union {
        short a[TILE_R * LDA];   // 50688 B : bf16 h1 (A-tile)
        float h[TILE_R * LDH];   // 49920 B : fp32 h2 staging for the mean
    } u;
    __shared__ float xt[TILE_B * 36];   // neighbor obs slice, fp32

    const int tid  = threadIdx.x;
    const int wave = tid >> 6;
    const int lane = tid & 63;
    const int q    = lane >> 4;    // quad
    const int c16  = lane & 15;

    // ---- persistent B fragments: wave owns cols [wave*64, wave*64+64).
    // B layout for 16x16x32: lane holds B[k=q*8+j][n=lane&15] -> read W2T[n][k..k+7].
    bf16x8 Bf[8][4];
    #pragma unroll
    for (int kk = 0; kk < 8; ++kk) {
        #pragma unroll
        for (int ct = 0; ct < 4; ++ct) {
            const int n = wave * 64 + ct * 16 + c16;
            const int k = kk * 32 + q * 8;
            Bf[kk][ct] = *(const bf16x8*)(w2t + n * 256 + k);
        }
    }

    // ---- layer-1 weights for this thread's 4 columns (j0..j0+3)
    const int j0 = (tid & 63) * 4;
    const int rg = wave;                 // rows rg, rg+4, ..., rg+44
    float w1r[6][4], b1r[4], b2r[4];
    #pragma unroll
    for (int k = 0; k < 6; ++k)
        #pragma unroll
        for (int c = 0; c < 4; ++c) w1r[k][c] = W1[k * 256 + j0 + c];
    #pragma unroll
    for (int c = 0; c < 4; ++c) b1r[c] = b1[j0 + c];
    #pragma unroll
    for (int ct = 0; ct < 4; ++ct) b2r[ct] = b2[wave * 64 + ct * 16 + c16];

    for (int tile = blockIdx.x; tile < NTILES; tile += gridDim.x) {
        const int b0 = tile * TILE_B;

        // stage x: 8 batches x 36 neighbor-features (fp32)
        for (int i = tid; i < TILE_B * 36; i += 256) {
            const int b = i / 36, o = i - b * 36;
            xt[i] = obs[(b0 + b) * OBSD + SELFD + o];
        }
        __syncthreads();

        // ---- layer 1: h1 = tanh(x @ W1 + b1) -> bf16 A-tile in LDS
        #pragma unroll
        for (int i = 0; i < 12; ++i) {
            const int r  = rg + i * 4;
            const int bl = r / 6;
            const int nn = r - bl * 6;
            const float* xv = &xt[bl * 36 + nn * 6];   // broadcast within wave
            short hs[4];
            #pragma unroll
            for (int c = 0; c < 4; ++c) {
                float s = b1r[c];
                #pragma unroll
                for (int k = 0; k < 6; ++k) s = fmaf(xv[k], w1r[k][c], s);
                hs[c] = f2bf(fast_tanh(s));
            }
            *(s16x4*)&u.a[r * LDA + j0] = (s16x4){hs[0], hs[1], hs[2], hs[3]};
        }
        __syncthreads();

        // ---- layer 2: (48 x 256) @ (256 x 256), wave does 48 x 64
        f32x4 acc[3][4];
        #pragma unroll
        for (int rt = 0; rt < 3; ++rt)
            #pragma unroll
            for (int ct = 0; ct < 4; ++ct) acc[rt][ct] = (f32x4){0.f, 0.f, 0.f, 0.f};

        #pragma unroll
        for (int kk = 0; kk < 8; ++kk) {
            bf16x8 Af[3];   // A layout: lane holds A[m=lane&15][k=q*8+j]
            #pragma unroll
            for (int rt = 0; rt < 3; ++rt)
                Af[rt] = *(const bf16x8*)&u.a[(rt * 16 + c16) * LDA + kk * 32 + q * 8];
            #pragma unroll
            for (int rt = 0; rt < 3; ++rt)
                #pragma unroll
                for (int ct = 0; ct < 4; ++ct)
                    acc[rt][ct] = __builtin_amdgcn_mfma_f32_16x16x32_bf16(
                        Af[rt], Bf[kk][ct], acc[rt][ct], 0, 0, 0);
        }
        __syncthreads();   // all ds_reads of u.a done before u.h writes (aliased)

        // ---- epilogue: bias + tanh -> fp32 staging.
        // C/D layout: col = lane&15, row = q*4 + reg.
        #pragma unroll
        for (int rt = 0; rt < 3; ++rt) {
            #pragma unroll
            for (int ct = 0; ct < 4; ++ct) {
                const int col = wave * 64 + ct * 16 + c16;
                #pragma unroll
                for (int g = 0; g < 4; ++g) {
                    const int row = rt * 16 + q * 4 + g;
                    u.h[row * LDH + col] = fast_tanh(acc[rt][ct][g] + b2r[ct]);
                }
            }
        }
        __syncthreads();

        // ---- mean over 6 neighbors; coalesced fp32 store
        #pragma unroll
        for (int bl = 0; bl < TILE_B; ++bl) {
            float s = 0.f;
            #pragma unroll
            for (int n = 0; n < 6; ++n) s += u.h[(bl * 6 + n) * LDH + tid];
            out[(b0 + bl) * HID + tid] = s * (1.0f / 6.0f);
        }
        // next iteration's u.a writes are fenced by the sync after the x-stage
    }
}

extern "C" void kernel_launch(void* const* d_in, const int* in_sizes, int n_in,
                              void* d_out, int out_size, void* d_ws, size_t ws_size,
                              hipStream_t stream) {
    // inputs: 0 self_obs (unused), 1 obs, 2 W1, 3 b1, 4 W2, 5 b2, 6/7 scalars
    const float* obs = (const float*)d_in[1];
    const float* W1  = (const float*)d_in[2];
    const float* b1  = (const float*)d_in[3];
    const float* W2  = (const float*)d_in[4];
    const float* b2  = (const float*)d_in[5];
    float* outp = (float*)d_out;
    short* w2t  = (short*)d_ws;   // 128 KiB

    prep_w2t<<<256, 256, 0, stream>>>(W2, w2t);
    qenc_main<<<GRID_WG, 256, 0, stream>>>(obs, W1, b1, w2t, b2, outp);
}